// Round 19
// baseline (144.539 us; speedup 1.0000x reference)
//
#include <hip/hip_runtime.h>
#include <math.h>

// (B,C,H,W) = (16,64,256,256)
// out[b,d,hw] = relu( rrelu( sum_c mix[d,c]*softmax_c(x)[b,c,hw] + bias[d] ) + 0.1*x[b,d,hw] )
#define HWSZ 65536

typedef __bf16 bf16x8 __attribute__((ext_vector_type(8)));
typedef float f32x4 __attribute__((ext_vector_type(4)));
typedef short short4v __attribute__((ext_vector_type(4)));

__global__ __launch_bounds__(256) void cvt_mix_kernel(const float* __restrict__ mix,
                                                      __bf16* __restrict__ mixb) {
    int i = blockIdx.x * 256 + threadIdx.x;   // 4096 elements
    mixb[i] = (__bf16)mix[i];
}

// r19 = r18 with the tr_read addressing FIXED: ds_read_b64_tr_b16 needs a
// PER-LANE address (base + lane*8); uniform addr returns lane-0's data to all
// lanes (m162: "no internal lane offset") — that was r18's absmax=0.69 bug.
// Swapped MFMA orientation: A = e-tile (rows=px), B = mix (cols=d); C/D gives
// each lane 4 CONSECUTIVE pixels of one d-row -> dwordx4 stores (16 vs 64).
__global__ __launch_bounds__(256) void fused_kernel(
    const float* __restrict__ x, const __bf16* __restrict__ mixb,
    const float* __restrict__ bias, float* __restrict__ out)
{
    // element (px,c) at byte (c>>4)*2048 + (px>>2)*128 + (px&3)*32 + (c&15)*2
    __shared__ __bf16 sT[4][4096];                // 8KB per wave, wave-private
    const int tid  = threadIdx.x;
    const int wid  = tid >> 6;
    const int lane = tid & 63;
    const int waveg = blockIdx.x * 4 + wid;       // 16384 waves, 64 px each
    const int b   = waveg >> 10;
    const int hw0 = (waveg & 1023) << 6;
    const size_t ibase = (size_t)b * (64 * HWSZ) + hw0;
    char* myb = (char*)&sT[wid][0];
    const int l15 = lane & 15, lhi = lane >> 4;

    const float LOG2E = 1.44269504088896340736f;
    const float LN2   = 0.69314718055994530942f;

    // ---- phase 1 (r17 exact): 64-load burst, no-max exp, sum ----
    const float* xp = x + ibase + lane;
    float e[64];
#pragma unroll
    for (int c = 0; c < 64; ++c) e[c] = xp[(size_t)c << 16];   // coalesced burst

    float s0 = 0.f, s1 = 0.f, s2 = 0.f, s3 = 0.f;
#pragma unroll
    for (int c = 0; c < 64; c += 4) {
        e[c]     = __builtin_exp2f(e[c]     * LOG2E); s0 += e[c];
        e[c + 1] = __builtin_exp2f(e[c + 1] * LOG2E); s1 += e[c + 1];
        e[c + 2] = __builtin_exp2f(e[c + 2] * LOG2E); s2 += e[c + 2];
        e[c + 3] = __builtin_exp2f(e[c + 3] * LOG2E); s3 += e[c + 3];
    }
    const float inv = 1.f / ((s0 + s1) + (s2 + s3));

    // ---- tile write: lane owns px=lane; 32B per ch16-block = 2x ds_write_b128 ----
    {
        char* wbase = myb + (lane >> 2) * 128 + (lane & 3) * 32;
#pragma unroll
        for (int cb = 0; cb < 4; ++cb) {
            bf16x8 v0, v1;
#pragma unroll
            for (int i = 0; i < 8; ++i) {
                v0[i] = (__bf16)e[cb * 16 + i];
                v1[i] = (__bf16)e[cb * 16 + 8 + i];
            }
            *reinterpret_cast<bf16x8*>(wbase + cb * 2048)      = v0;
            *reinterpret_cast<bf16x8*>(wbase + cb * 2048 + 16) = v1;
        }
    }
    asm volatile("s_waitcnt lgkmcnt(0)" ::: "memory");  // wave-local visibility

    // bias for this lane's 4 d-columns (d = nt*16 + l15); L1-hot
    float bd[4];
#pragma unroll
    for (int nt = 0; nt < 4; ++nt) bd[nt] = bias[nt * 16 + l15];

    // per-lane tr_read address base: +lane*8 (the r18 bug was omitting this)
    const unsigned trbase = (unsigned)(uintptr_t)myb + (unsigned)(lane * 8);

    // ---- phases 2+3 in two px-half passes (acc[2][4] = 32 VGPR) ----
#pragma unroll
    for (int p = 0; p < 2; ++p) {
        // inv for px = (2p+q)*16 + lhi*4 + r (lane px computed it)
        float ivp[2][4];
#pragma unroll
        for (int q = 0; q < 2; ++q)
#pragma unroll
            for (int r = 0; r < 4; ++r)
                ivp[q][r] = __shfl(inv, (2 * p + q) * 16 + lhi * 4 + r, 64);

        f32x4 acc[2][4] = {};
#pragma unroll
        for (int kt = 0; kt < 2; ++kt) {
            // B = mix: lane holds row d=nt*16+l15, cols c=kt*32+lhi*8..+7 (L1-hot)
            bf16x8 Bf[4];
            const __bf16* mb = mixb + l15 * 64 + kt * 32 + lhi * 8;
#pragma unroll
            for (int nt = 0; nt < 4; ++nt)
                Bf[nt] = *reinterpret_cast<const bf16x8*>(mb + nt * 16 * 64);
#pragma unroll
            for (int q = 0; q < 2; ++q) {
                const int mt = 2 * p + q;
                // A = e-tile: row px=mt*16+l15, same c-slice; 16B contiguous
                const bf16x8 Af = *reinterpret_cast<const bf16x8*>(
                    myb + (2 * kt + (lhi >> 1)) * 2048
                        + (mt * 4 + (l15 >> 2)) * 128
                        + (l15 & 3) * 32 + (lhi & 1) * 16);
#pragma unroll
                for (int nt = 0; nt < 4; ++nt)
                    acc[q][nt] = __builtin_amdgcn_mfma_f32_16x16x32_bf16(
                        Af, Bf[nt], acc[q][nt], 0, 0, 0);
            }
        }

        // epilogue: lane holds (d = nt*16+l15, px = mt*16+lhi*4+r) -> x4 stores
#pragma unroll
        for (int q = 0; q < 2; ++q) {
            const int mt = 2 * p + q;
            short4v sv4[4];
#pragma unroll
            for (int nt = 0; nt < 4; ++nt) {
                // per-lane addr: group lhi*128 + l15*8; HW returns elem j at
                // group_base + (l&15)*2 + j*32  ==  e[px=mt*16+lhi*4+j][d=nt*16+l15]
                unsigned a = trbase + (unsigned)(nt * 2048 + mt * 512);
                asm volatile("ds_read_b64_tr_b16 %0, %1" : "=&v"(sv4[nt]) : "v"(a));
            }
            asm volatile("s_waitcnt lgkmcnt(0)" ::: "memory");
            __builtin_amdgcn_sched_barrier(0);           // rule #18: pin consume after wait
#pragma unroll
            for (int nt = 0; nt < 4; ++nt) {
                f32x4 vv;
#pragma unroll
                for (int r = 0; r < 4; ++r) {
                    float mixed = fmaf(acc[q][nt][r], ivp[q][r], bd[nt]);
                    float act = fmaxf(mixed, 0.2f * mixed);          // RReLU (slope>0)
                    unsigned u = ((unsigned)(unsigned short)sv4[nt][r]) << 16;
                    float ev = __builtin_bit_cast(float, u);         // bf16 -> f32
                    float xv = LN2 * __builtin_log2f(ev);            // x = ln(e_raw)
                    vv[r] = fmaxf(fmaf(0.1f, xv, act), 0.f);
                }
                const int d0  = nt * 16 + l15;
                const int px0 = mt * 16 + lhi * 4;
                *reinterpret_cast<f32x4*>(out + ibase + (size_t)d0 * HWSZ + px0) = vv;
            }
        }
    }
}

extern "C" void kernel_launch(void* const* d_in, const int* in_sizes, int n_in,
                              void* d_out, int out_size, void* d_ws, size_t ws_size,
                              hipStream_t stream) {
    const float* x    = (const float*)d_in[0];
    const float* mix  = (const float*)d_in[1];
    const float* bias = (const float*)d_in[2];
    float* out = (float*)d_out;
    __bf16* mixb = (__bf16*)d_ws;    // 4096 * 2B
    (void)in_sizes; (void)n_in; (void)out_size; (void)ws_size;

    cvt_mix_kernel<<<dim3(16), dim3(256), 0, stream>>>(mix, mixb);
    fused_kernel<<<dim3(4096), dim3(256), 0, stream>>>(x, mixb, bias, out);
}